// Round 5
// baseline (845.684 us; speedup 1.0000x reference)
//
#include <hip/hip_runtime.h>

// VecInt: scaling-and-squaring integration of a stationary velocity field.
// vec' = vec/2^7; repeat 7x: vec = vec + grid_sample3d(vec, vec + ident).
// Fixed problem shape: (1, 3, 160, 192, 160) float32.
//
// Numerics: per-step arithmetic in double, f32 stores; accumulation order is
// bitwise-identical across all kernel variants (absmax 4.39e-3 vs 5.16e-3).
//
// Perf model (R4 confirmed): divergent-address vector loads cost ~1 lookup
// per lane per cycle per CU (~64 cyc/inst) with NO same-line coalescing
// credit — early coherent steps time identically to late random steps.
// Floor for the AoS4 global-gather step: 8 insts/voxel -> ~64 us. Steps 2-7
// sit on that floor. Step 1 (offset sigma ~0.7 voxel, max ~4) is the only
// step with a boundable halo -> LDS-staged kernel (coalesced staging loads
// are exempt from the per-lane cost), fused with the SoA->AoS4 repack.
// Step 7 fuses the AoS4->SoA unpack (writes SoA directly).

constexpr int D = 160;
constexpr int H = 192;
constexpr int W = 160;
constexpr int HW = H * W;        // 30720
constexpr int DHW = D * HW;      // 4915200
constexpr int NSTEPS = 7;

// ---- mid-step tiling (global-gather AoS4 kernel) ----
constexpr int BX = 32, BY = 8;
constexpr int NTX = W / BX;      // 5
constexpr int NTY = H / BY;      // 24
constexpr int NTZ = D;           // 160
constexpr int NBLK = NTX * NTY * NTZ;   // 19200
constexpr int NXCD = 8;
constexpr int BLK_PER_XCD = NBLK / NXCD; // 2400

// ---- step-1 LDS tiling ----
constexpr int S1_TX = 32, S1_TY = 8, S1_TZ = 2;
constexpr int S1_HX = 3, S1_HY = 4, S1_HZ = 3;   // halo; offsets beyond -> fallback
constexpr int S1_SX = S1_TX + 2 * S1_HX;  // 38
constexpr int S1_SY = S1_TY + 2 * S1_HY;  // 16
constexpr int S1_SZ = S1_TZ + 2 * S1_HZ;  // 8
constexpr int S1_SXY = S1_SX * S1_SY;     // 608
constexpr int S1_CH = S1_SXY * S1_SZ;     // 4864 floats per channel
constexpr int S1_TOT = 3 * S1_CH;         // 14592 floats = 58.4 KB
constexpr int S1_NTX = W / S1_TX;         // 5
constexpr int S1_NTY = H / S1_TY;         // 24
constexpr int S1_NTZ = D / S1_TZ;         // 80
constexpr int S1_NBLK = S1_NTX * S1_NTY * S1_NTZ;  // 9600

__device__ __forceinline__ void decode_tile(int bid, int& w, int& h, int& d) {
    // XCD-slab swizzle: HW round-robins blockIdx.x across 8 XCDs; give XCD k
    // a contiguous tile range (z-slab) for L2 locality.
    int sid = (bid & (NXCD - 1)) * BLK_PER_XCD + (bid >> 3);
    int tx  = sid % NTX;
    int t2  = sid / NTX;
    int ty  = t2 % NTY;
    int tz  = t2 / NTY;
    w = tx * BX + threadIdx.x;
    h = ty * BY + threadIdx.y;
    d = tz;
}

// Shared per-voxel trilinear machinery (double precision, fixed eval order).
struct TriSetup {
    int xc0, xc1, yc0, yc1, zc0, zc1, bx;
    bool s0hi, s1lo;
    double w000, w001, w010, w011, w100, w101, w110, w111;
};

__device__ __forceinline__ TriSetup tri_setup(double vz, double vy, double vx,
                                              double sd, int d, int h, int w) {
    TriSetup t;
    double z = vz * (sd * 0.5 * (double)(D - 1)) + (double)d;
    double y = vy * (sd * 0.5 * (double)(H - 1)) + (double)h;
    double x = vx * (sd * 0.5 * (double)(W - 1)) + (double)w;

    double z0f = floor(z), y0f = floor(y), x0f = floor(x);
    int z0 = (int)z0f, y0 = (int)y0f, x0 = (int)x0f;
    int z1 = z0 + 1,   y1 = y0 + 1,   x1 = x0 + 1;
    double fz = z - z0f, fy = y - y0f, fx = x - x0f;

    bool zv0 = ((unsigned)z0 < (unsigned)D), zv1 = ((unsigned)z1 < (unsigned)D);
    bool yv0 = ((unsigned)y0 < (unsigned)H), yv1 = ((unsigned)y1 < (unsigned)H);
    bool xv0 = ((unsigned)x0 < (unsigned)W), xv1 = ((unsigned)x1 < (unsigned)W);

    t.zc0 = min(max(z0, 0), D - 1); t.zc1 = min(max(z1, 0), D - 1);
    t.yc0 = min(max(y0, 0), H - 1); t.yc1 = min(max(y1, 0), H - 1);
    t.xc0 = min(max(x0, 0), W - 1); t.xc1 = min(max(x1, 0), W - 1);

    double wz0 = 1.0 - fz, wz1 = fz;
    double wy0 = 1.0 - fy, wy1 = fy;
    double wx0 = 1.0 - fx, wx1 = fx;

    t.w000 = (zv0 && yv0 && xv0) ? wz0 * wy0 * wx0 : 0.0;
    t.w001 = (zv0 && yv0 && xv1) ? wz0 * wy0 * wx1 : 0.0;
    t.w010 = (zv0 && yv1 && xv0) ? wz0 * wy1 * wx0 : 0.0;
    t.w011 = (zv0 && yv1 && xv1) ? wz0 * wy1 * wx1 : 0.0;
    t.w100 = (zv1 && yv0 && xv0) ? wz1 * wy0 * wx0 : 0.0;
    t.w101 = (zv1 && yv0 && xv1) ? wz1 * wy0 * wx1 : 0.0;
    t.w110 = (zv1 && yv1 && xv0) ? wz1 * wy1 * wx0 : 0.0;
    t.w111 = (zv1 && yv1 && xv1) ? wz1 * wy1 * wx1 : 0.0;

    t.bx   = min(max(x0, 0), W - 2);
    t.s0hi = (t.xc0 != t.bx);
    t.s1lo = (t.xc1 == t.bx);
    return t;
}

// ---------- mid steps: AoS4 global-gather (steps 2..6) ----------

__global__ __launch_bounds__(256)
void vecint_step4(const float4* __restrict__ src, float4* __restrict__ dst, float s) {
    int w, h, d;
    decode_tile(blockIdx.x, w, h, d);
    int p = d * HW + h * W + w;

    float4 ctr = src[p];
    double vz = (double)ctr.x, vy = (double)ctr.y, vx = (double)ctr.z;
    double sd = (double)s;

    TriSetup t = tri_setup(vz, vy, vx, sd, d, h, w);

    int r00 = t.zc0 * HW + t.yc0 * W;
    int r01 = t.zc0 * HW + t.yc1 * W;
    int r10 = t.zc1 * HW + t.yc0 * W;
    int r11 = t.zc1 * HW + t.yc1 * W;

    float4 f00a = src[r00 + t.bx], f00b = src[r00 + t.bx + 1];
    float4 f01a = src[r01 + t.bx], f01b = src[r01 + t.bx + 1];
    float4 f10a = src[r10 + t.bx], f10b = src[r10 + t.bx + 1];
    float4 f11a = src[r11 + t.bx], f11b = src[r11 + t.bx + 1];

    float4 x000 = t.s0hi ? f00b : f00a;  float4 x001 = t.s1lo ? f00a : f00b;
    float4 x010 = t.s0hi ? f01b : f01a;  float4 x011 = t.s1lo ? f01a : f01b;
    float4 x100 = t.s0hi ? f10b : f10a;  float4 x101 = t.s1lo ? f10a : f10b;
    float4 x110 = t.s0hi ? f11b : f11a;  float4 x111 = t.s1lo ? f11a : f11b;

    float4 o;
    {
        double acc = vz;
        acc += t.w000 * (double)x000.x; acc += t.w001 * (double)x001.x;
        acc += t.w010 * (double)x010.x; acc += t.w011 * (double)x011.x;
        acc += t.w100 * (double)x100.x; acc += t.w101 * (double)x101.x;
        acc += t.w110 * (double)x110.x; acc += t.w111 * (double)x111.x;
        o.x = (float)(sd * acc);
    }
    {
        double acc = vy;
        acc += t.w000 * (double)x000.y; acc += t.w001 * (double)x001.y;
        acc += t.w010 * (double)x010.y; acc += t.w011 * (double)x011.y;
        acc += t.w100 * (double)x100.y; acc += t.w101 * (double)x101.y;
        acc += t.w110 * (double)x110.y; acc += t.w111 * (double)x111.y;
        o.y = (float)(sd * acc);
    }
    {
        double acc = vx;
        acc += t.w000 * (double)x000.z; acc += t.w001 * (double)x001.z;
        acc += t.w010 * (double)x010.z; acc += t.w011 * (double)x011.z;
        acc += t.w100 * (double)x100.z; acc += t.w101 * (double)x101.z;
        acc += t.w110 * (double)x110.z; acc += t.w111 * (double)x111.z;
        o.z = (float)(sd * acc);
    }
    o.w = 0.0f;
    dst[p] = o;
}

// ---------- step 7: AoS4 gather, SoA store (fused unpack) ----------

__global__ __launch_bounds__(256)
void vecint_step7(const float4* __restrict__ src, float* __restrict__ dst) {
    int w, h, d;
    decode_tile(blockIdx.x, w, h, d);
    int p = d * HW + h * W + w;

    float4 ctr = src[p];
    double vz = (double)ctr.x, vy = (double)ctr.y, vx = (double)ctr.z;
    const double sd = 1.0;

    TriSetup t = tri_setup(vz, vy, vx, sd, d, h, w);

    int r00 = t.zc0 * HW + t.yc0 * W;
    int r01 = t.zc0 * HW + t.yc1 * W;
    int r10 = t.zc1 * HW + t.yc0 * W;
    int r11 = t.zc1 * HW + t.yc1 * W;

    float4 f00a = src[r00 + t.bx], f00b = src[r00 + t.bx + 1];
    float4 f01a = src[r01 + t.bx], f01b = src[r01 + t.bx + 1];
    float4 f10a = src[r10 + t.bx], f10b = src[r10 + t.bx + 1];
    float4 f11a = src[r11 + t.bx], f11b = src[r11 + t.bx + 1];

    float4 x000 = t.s0hi ? f00b : f00a;  float4 x001 = t.s1lo ? f00a : f00b;
    float4 x010 = t.s0hi ? f01b : f01a;  float4 x011 = t.s1lo ? f01a : f01b;
    float4 x100 = t.s0hi ? f10b : f10a;  float4 x101 = t.s1lo ? f10a : f10b;
    float4 x110 = t.s0hi ? f11b : f11a;  float4 x111 = t.s1lo ? f11a : f11b;

    {
        double acc = vz;
        acc += t.w000 * (double)x000.x; acc += t.w001 * (double)x001.x;
        acc += t.w010 * (double)x010.x; acc += t.w011 * (double)x011.x;
        acc += t.w100 * (double)x100.x; acc += t.w101 * (double)x101.x;
        acc += t.w110 * (double)x110.x; acc += t.w111 * (double)x111.x;
        dst[p] = (float)(sd * acc);
    }
    {
        double acc = vy;
        acc += t.w000 * (double)x000.y; acc += t.w001 * (double)x001.y;
        acc += t.w010 * (double)x010.y; acc += t.w011 * (double)x011.y;
        acc += t.w100 * (double)x100.y; acc += t.w101 * (double)x101.y;
        acc += t.w110 * (double)x110.y; acc += t.w111 * (double)x111.y;
        dst[p + DHW] = (float)(sd * acc);
    }
    {
        double acc = vx;
        acc += t.w000 * (double)x000.z; acc += t.w001 * (double)x001.z;
        acc += t.w010 * (double)x010.z; acc += t.w011 * (double)x011.z;
        acc += t.w100 * (double)x100.z; acc += t.w101 * (double)x101.z;
        acc += t.w110 * (double)x110.z; acc += t.w111 * (double)x111.z;
        dst[p + 2 * DHW] = (float)(sd * acc);
    }
}

// ---------- step 1: SoA input, LDS-staged gather, AoS4 store (fused pack) ----------

__global__ __launch_bounds__(256)
void vecint_step1(const float* __restrict__ src, float4* __restrict__ dst, float s) {
    __shared__ float lds[S1_TOT];

    int bid = blockIdx.x;
    int sid = (bid & (NXCD - 1)) * (S1_NBLK / NXCD) + (bid >> 3);
    int tx  = sid % S1_NTX;
    int t2  = sid / S1_NTX;
    int ty  = t2 % S1_NTY;
    int tz  = t2 / S1_NTY;
    int gx0 = tx * S1_TX, gy0 = ty * S1_TY, gz0 = tz * S1_TZ;
    int sx0 = gx0 - S1_HX, sy0 = gy0 - S1_HY, sz0 = gz0 - S1_HZ;

    int tid = threadIdx.y * S1_TX + threadIdx.x;

    // Stage SoA tile+halo (coalesced dword loads -> LDS). Cells outside the
    // volume are left unwritten; clamped corner indices never touch them.
    for (int k = 0; k < S1_TOT / 256; ++k) {
        int e  = tid + k * 256;
        int c  = e / S1_CH;
        int r  = e - c * S1_CH;
        int lz = r / S1_SXY;
        int r2 = r - lz * S1_SXY;
        int ly = r2 / S1_SX;
        int lx = r2 - ly * S1_SX;
        int x = sx0 + lx, y = sy0 + ly, z = sz0 + lz;
        if ((unsigned)x < (unsigned)W && (unsigned)y < (unsigned)H &&
            (unsigned)z < (unsigned)D)
            lds[e] = src[c * DHW + z * HW + y * W + x];
    }
    __syncthreads();

    double sd = (double)s;
    int w = gx0 + threadIdx.x;
    int h = gy0 + threadIdx.y;

    for (int iz = 0; iz < S1_TZ; ++iz) {
        int d = gz0 + iz;
        int p = d * HW + h * W + w;

        // Center values from LDS (bit-identical to the global values).
        int lc = (iz + S1_HZ) * S1_SXY + ((int)threadIdx.y + S1_HY) * S1_SX +
                 (int)threadIdx.x + S1_HX;
        float vzf = lds[lc];
        float vyf = lds[lc + S1_CH];
        float vxf = lds[lc + 2 * S1_CH];
        double vz = (double)vzf, vy = (double)vyf, vx = (double)vxf;

        TriSetup t = tri_setup(vz, vy, vx, sd, d, h, w);

        bool inh = (t.bx >= sx0) && (t.bx + 1 <= sx0 + S1_SX - 1) &&
                   (t.yc0 >= sy0) && (t.yc1 <= sy0 + S1_SY - 1) &&
                   (t.zc0 >= sz0) && (t.zc1 <= sz0 + S1_SZ - 1);

        // Corner values q[corner 000..111][channel], identical bits either path.
        float q[8][3];
        if (inh) {
            int lbx = t.bx - sx0;
            int l00 = (t.zc0 - sz0) * S1_SXY + (t.yc0 - sy0) * S1_SX + lbx;
            int l01 = (t.zc0 - sz0) * S1_SXY + (t.yc1 - sy0) * S1_SX + lbx;
            int l10 = (t.zc1 - sz0) * S1_SXY + (t.yc0 - sy0) * S1_SX + lbx;
            int l11 = (t.zc1 - sz0) * S1_SXY + (t.yc1 - sy0) * S1_SX + lbx;
            #pragma unroll
            for (int c = 0; c < 3; ++c) {
                int b = c * S1_CH;
                float a00 = lds[b + l00], b00 = lds[b + l00 + 1];
                float a01 = lds[b + l01], b01 = lds[b + l01 + 1];
                float a10 = lds[b + l10], b10 = lds[b + l10 + 1];
                float a11 = lds[b + l11], b11 = lds[b + l11 + 1];
                q[0][c] = t.s0hi ? b00 : a00;  q[1][c] = t.s1lo ? a00 : b00;
                q[2][c] = t.s0hi ? b01 : a01;  q[3][c] = t.s1lo ? a01 : b01;
                q[4][c] = t.s0hi ? b10 : a10;  q[5][c] = t.s1lo ? a10 : b10;
                q[6][c] = t.s0hi ? b11 : a11;  q[7][c] = t.s1lo ? a11 : b11;
            }
        } else {
            int r00 = t.zc0 * HW + t.yc0 * W;
            int r01 = t.zc0 * HW + t.yc1 * W;
            int r10 = t.zc1 * HW + t.yc0 * W;
            int r11 = t.zc1 * HW + t.yc1 * W;
            #pragma unroll
            for (int c = 0; c < 3; ++c) {
                const float* sc = src + c * DHW;
                q[0][c] = sc[r00 + t.xc0];  q[1][c] = sc[r00 + t.xc1];
                q[2][c] = sc[r01 + t.xc0];  q[3][c] = sc[r01 + t.xc1];
                q[4][c] = sc[r10 + t.xc0];  q[5][c] = sc[r10 + t.xc1];
                q[6][c] = sc[r11 + t.xc0];  q[7][c] = sc[r11 + t.xc1];
            }
        }

        float4 o;
        {
            double acc = vz;
            acc += t.w000 * (double)q[0][0]; acc += t.w001 * (double)q[1][0];
            acc += t.w010 * (double)q[2][0]; acc += t.w011 * (double)q[3][0];
            acc += t.w100 * (double)q[4][0]; acc += t.w101 * (double)q[5][0];
            acc += t.w110 * (double)q[6][0]; acc += t.w111 * (double)q[7][0];
            o.x = (float)(sd * acc);
        }
        {
            double acc = vy;
            acc += t.w000 * (double)q[0][1]; acc += t.w001 * (double)q[1][1];
            acc += t.w010 * (double)q[2][1]; acc += t.w011 * (double)q[3][1];
            acc += t.w100 * (double)q[4][1]; acc += t.w101 * (double)q[5][1];
            acc += t.w110 * (double)q[6][1]; acc += t.w111 * (double)q[7][1];
            o.y = (float)(sd * acc);
        }
        {
            double acc = vx;
            acc += t.w000 * (double)q[0][2]; acc += t.w001 * (double)q[1][2];
            acc += t.w010 * (double)q[2][2]; acc += t.w011 * (double)q[3][2];
            acc += t.w100 * (double)q[4][2]; acc += t.w101 * (double)q[5][2];
            acc += t.w110 * (double)q[6][2]; acc += t.w111 * (double)q[7][2];
            o.z = (float)(sd * acc);
        }
        o.w = 0.0f;
        dst[p] = o;
    }
}

// ---------- fallback SoA step (used only if ws too small) ----------

__global__ __launch_bounds__(256)
void vecint_step(const float* __restrict__ src, float* __restrict__ dst, float s) {
    int w, h, d;
    decode_tile(blockIdx.x, w, h, d);
    int p = d * HW + h * W + w;

    double vz = (double)src[p];
    double vy = (double)src[p + DHW];
    double vx = (double)src[p + 2 * DHW];
    double sd = (double)s;

    TriSetup t = tri_setup(vz, vy, vx, sd, d, h, w);

    int r00 = t.zc0 * HW + t.yc0 * W;
    int r01 = t.zc0 * HW + t.yc1 * W;
    int r10 = t.zc1 * HW + t.yc0 * W;
    int r11 = t.zc1 * HW + t.yc1 * W;

    double ctr[3] = {vz, vy, vx};
    #pragma unroll
    for (int c = 0; c < 3; ++c) {
        const float* sc = src + c * DHW;
        double acc = ctr[c];
        acc += t.w000 * (double)sc[r00 + t.xc0];
        acc += t.w001 * (double)sc[r00 + t.xc1];
        acc += t.w010 * (double)sc[r01 + t.xc0];
        acc += t.w011 * (double)sc[r01 + t.xc1];
        acc += t.w100 * (double)sc[r10 + t.xc0];
        acc += t.w101 * (double)sc[r10 + t.xc1];
        acc += t.w110 * (double)sc[r11 + t.xc0];
        acc += t.w111 * (double)sc[r11 + t.xc1];
        dst[c * DHW + p] = (float)(sd * acc);
    }
}

extern "C" void kernel_launch(void* const* d_in, const int* in_sizes, int n_in,
                              void* d_out, int out_size, void* d_ws, size_t ws_size,
                              hipStream_t stream) {
    const float* vin = (const float*)d_in[0];
    float* out = (float*)d_out;

    const float s = 1.0f / 128.0f;  // 1/2^NSTEPS, exact power of 2

    dim3 tile_block(BX, BY, 1);
    dim3 tile_grid(NBLK, 1, 1);
    dim3 s1_block(S1_TX, S1_TY, 1);
    dim3 s1_grid(S1_NBLK, 1, 1);

    const size_t aos4_bytes = (size_t)DHW * sizeof(float4);

    if (ws_size >= 2 * aos4_bytes) {
        float4* A = (float4*)d_ws;
        float4* B = A + DHW;

        // step 1 (fused SoA->AoS4 repack + scale fold), writes A
        vecint_step1<<<s1_grid, s1_block, 0, stream>>>(vin, A, s);
        // steps 2..6: ping-pong
        vecint_step4<<<tile_grid, tile_block, 0, stream>>>(A, B, 1.0f);
        vecint_step4<<<tile_grid, tile_block, 0, stream>>>(B, A, 1.0f);
        vecint_step4<<<tile_grid, tile_block, 0, stream>>>(A, B, 1.0f);
        vecint_step4<<<tile_grid, tile_block, 0, stream>>>(B, A, 1.0f);
        vecint_step4<<<tile_grid, tile_block, 0, stream>>>(A, B, 1.0f);
        // step 7 (fused AoS4->SoA unpack), writes d_out
        vecint_step7<<<tile_grid, tile_block, 0, stream>>>(B, out);
    } else {
        // Fallback: SoA ping-pong d_out <-> d_ws.
        float* ws = (float*)d_ws;
        vecint_step<<<tile_grid, tile_block, 0, stream>>>(vin, out, s);
        const float* srcs[6] = {out, ws, out, ws, out, ws};
        float*       dsts[6] = {ws, out, ws, out, ws, out};
        for (int i = 0; i < NSTEPS - 1; ++i)
            vecint_step<<<tile_grid, tile_block, 0, stream>>>(srcs[i], dsts[i], 1.0f);
    }
}

// Round 6
// 540.193 us; speedup vs baseline: 1.5655x; 1.5655x over previous
//
#include <hip/hip_runtime.h>

// VecInt: scaling-and-squaring integration of a stationary velocity field.
// vec' = vec/2^7; repeat 7x: vec = vec + grid_sample3d(vec, vec + ident).
// Fixed problem shape: (1, 3, 160, 192, 160) float32.
//
// Numerics: per-step arithmetic in double, f32 stores; accumulation order is
// bitwise-identical across all kernel variants (absmax 4.39e-3 vs 5.16e-3).
//
// Perf model (R4/R5 confirmed): divergent-address vector loads cost ~1 lane-
// lookup/cycle/CU (~64 cyc per wave inst) with no same-line coalescing credit.
// AoS4 (float4/voxel) gather step = 8 divergent insts/voxel -> ~64 us floor,
// measured 75 us/step incl. center load + store. LDS staging (R5) LOST badly:
// 3-channel f32 halo economics give 9.5x staging overhead at feasible tile
// sizes -> 396 us. Structure: repack -> 6x AoS4 gather -> gather+SoA store.

constexpr int D = 160;
constexpr int H = 192;
constexpr int W = 160;
constexpr int HW = H * W;        // 30720
constexpr int DHW = D * HW;      // 4915200

constexpr int BX = 32, BY = 8;
constexpr int NTX = W / BX;      // 5
constexpr int NTY = H / BY;      // 24
constexpr int NTZ = D;           // 160
constexpr int NBLK = NTX * NTY * NTZ;   // 19200
constexpr int NXCD = 8;
constexpr int BLK_PER_XCD = NBLK / NXCD; // 2400

__device__ __forceinline__ void decode_tile(int bid, int& w, int& h, int& d) {
    // XCD-slab swizzle: HW round-robins blockIdx.x across 8 XCDs; give XCD k
    // a contiguous tile range (z-slab) for L2 locality.
    int sid = (bid & (NXCD - 1)) * BLK_PER_XCD + (bid >> 3);
    int tx  = sid % NTX;
    int t2  = sid / NTX;
    int ty  = t2 % NTY;
    int tz  = t2 / NTY;
    w = tx * BX + threadIdx.x;
    h = ty * BY + threadIdx.y;
    d = tz;
}

struct TriSetup {
    int zc0, zc1, yc0, yc1, bx;
    bool s0hi, s1lo;
    double w000, w001, w010, w011, w100, w101, w110, w111;
};

__device__ __forceinline__ TriSetup tri_setup(double vz, double vy, double vx,
                                              double sd, int d, int h, int w) {
    TriSetup t;
    double z = vz * (sd * 0.5 * (double)(D - 1)) + (double)d;
    double y = vy * (sd * 0.5 * (double)(H - 1)) + (double)h;
    double x = vx * (sd * 0.5 * (double)(W - 1)) + (double)w;

    double z0f = floor(z), y0f = floor(y), x0f = floor(x);
    int z0 = (int)z0f, y0 = (int)y0f, x0 = (int)x0f;
    int z1 = z0 + 1,   y1 = y0 + 1,   x1 = x0 + 1;
    double fz = z - z0f, fy = y - y0f, fx = x - x0f;

    bool zv0 = ((unsigned)z0 < (unsigned)D), zv1 = ((unsigned)z1 < (unsigned)D);
    bool yv0 = ((unsigned)y0 < (unsigned)H), yv1 = ((unsigned)y1 < (unsigned)H);
    bool xv0 = ((unsigned)x0 < (unsigned)W), xv1 = ((unsigned)x1 < (unsigned)W);

    t.zc0 = min(max(z0, 0), D - 1); t.zc1 = min(max(z1, 0), D - 1);
    t.yc0 = min(max(y0, 0), H - 1); t.yc1 = min(max(y1, 0), H - 1);
    int xc0 = min(max(x0, 0), W - 1);
    int xc1 = min(max(x1, 0), W - 1);

    double wz0 = 1.0 - fz, wz1 = fz;
    double wy0 = 1.0 - fy, wy1 = fy;
    double wx0 = 1.0 - fx, wx1 = fx;

    t.w000 = (zv0 && yv0 && xv0) ? wz0 * wy0 * wx0 : 0.0;
    t.w001 = (zv0 && yv0 && xv1) ? wz0 * wy0 * wx1 : 0.0;
    t.w010 = (zv0 && yv1 && xv0) ? wz0 * wy1 * wx0 : 0.0;
    t.w011 = (zv0 && yv1 && xv1) ? wz0 * wy1 * wx1 : 0.0;
    t.w100 = (zv1 && yv0 && xv0) ? wz1 * wy0 * wx0 : 0.0;
    t.w101 = (zv1 && yv0 && xv1) ? wz1 * wy0 * wx1 : 0.0;
    t.w110 = (zv1 && yv1 && xv0) ? wz1 * wy1 * wx0 : 0.0;
    t.w111 = (zv1 && yv1 && xv1) ? wz1 * wy1 * wx1 : 0.0;

    // x-pair base: both src[r+bx], src[r+bx+1] in-row; branch-free select
    // reproduces exactly the clamped-x0/x1 values.
    t.bx   = min(max(x0, 0), W - 2);
    t.s0hi = (xc0 != t.bx);
    t.s1lo = (xc1 == t.bx);
    return t;
}

// Gather the 8 corner float4s and produce the three accumulated channels.
__device__ __forceinline__ void gather_acc(const float4* __restrict__ src,
                                           const TriSetup& t,
                                           double vz, double vy, double vx,
                                           double sd,
                                           double& oz, double& oy, double& ox) {
    int r00 = t.zc0 * HW + t.yc0 * W;
    int r01 = t.zc0 * HW + t.yc1 * W;
    int r10 = t.zc1 * HW + t.yc0 * W;
    int r11 = t.zc1 * HW + t.yc1 * W;

    float4 f00a = src[r00 + t.bx], f00b = src[r00 + t.bx + 1];
    float4 f01a = src[r01 + t.bx], f01b = src[r01 + t.bx + 1];
    float4 f10a = src[r10 + t.bx], f10b = src[r10 + t.bx + 1];
    float4 f11a = src[r11 + t.bx], f11b = src[r11 + t.bx + 1];

    float4 x000 = t.s0hi ? f00b : f00a;  float4 x001 = t.s1lo ? f00a : f00b;
    float4 x010 = t.s0hi ? f01b : f01a;  float4 x011 = t.s1lo ? f01a : f01b;
    float4 x100 = t.s0hi ? f10b : f10a;  float4 x101 = t.s1lo ? f10a : f10b;
    float4 x110 = t.s0hi ? f11b : f11a;  float4 x111 = t.s1lo ? f11a : f11b;

    {
        double acc = vz;
        acc += t.w000 * (double)x000.x; acc += t.w001 * (double)x001.x;
        acc += t.w010 * (double)x010.x; acc += t.w011 * (double)x011.x;
        acc += t.w100 * (double)x100.x; acc += t.w101 * (double)x101.x;
        acc += t.w110 * (double)x110.x; acc += t.w111 * (double)x111.x;
        oz = sd * acc;
    }
    {
        double acc = vy;
        acc += t.w000 * (double)x000.y; acc += t.w001 * (double)x001.y;
        acc += t.w010 * (double)x010.y; acc += t.w011 * (double)x011.y;
        acc += t.w100 * (double)x100.y; acc += t.w101 * (double)x101.y;
        acc += t.w110 * (double)x110.y; acc += t.w111 * (double)x111.y;
        oy = sd * acc;
    }
    {
        double acc = vx;
        acc += t.w000 * (double)x000.z; acc += t.w001 * (double)x001.z;
        acc += t.w010 * (double)x010.z; acc += t.w011 * (double)x011.z;
        acc += t.w100 * (double)x100.z; acc += t.w101 * (double)x101.z;
        acc += t.w110 * (double)x110.z; acc += t.w111 * (double)x111.z;
        ox = sd * acc;
    }
}

// ---------- repack: SoA -> AoS4 (coalesced streams) ----------

__global__ __launch_bounds__(256)
void soa_to_aos4(const float* __restrict__ src, float4* __restrict__ dst) {
    int p = blockIdx.x * blockDim.x + threadIdx.x;
    if (p >= DHW) return;
    float4 v;
    v.x = src[p];
    v.y = src[p + DHW];
    v.z = src[p + 2 * DHW];
    v.w = 0.0f;
    dst[p] = v;
}

// ---------- steps 1..6: AoS4 -> AoS4 gather ----------
// FIRST=true folds the 1/128 scale (exact pow2); otherwise sd=1.0 and
// sd*acc == acc bitwise, so all variants share exact arithmetic.

template <bool FIRST>
__global__ __launch_bounds__(256)
void vecint_step4(const float4* __restrict__ src, float4* __restrict__ dst) {
    int w, h, d;
    decode_tile(blockIdx.x, w, h, d);
    int p = d * HW + h * W + w;

    float4 ctr = src[p];
    double vz = (double)ctr.x, vy = (double)ctr.y, vx = (double)ctr.z;
    const double sd = FIRST ? (1.0 / 128.0) : 1.0;

    TriSetup t = tri_setup(vz, vy, vx, sd, d, h, w);
    double oz, oy, ox;
    gather_acc(src, t, vz, vy, vx, sd, oz, oy, ox);

    float4 o;
    o.x = (float)oz; o.y = (float)oy; o.z = (float)ox; o.w = 0.0f;
    dst[p] = o;
}

// ---------- step 7: AoS4 gather, SoA store (fused unpack) ----------

__global__ __launch_bounds__(256)
void vecint_step7(const float4* __restrict__ src, float* __restrict__ dst) {
    int w, h, d;
    decode_tile(blockIdx.x, w, h, d);
    int p = d * HW + h * W + w;

    float4 ctr = src[p];
    double vz = (double)ctr.x, vy = (double)ctr.y, vx = (double)ctr.z;
    const double sd = 1.0;

    TriSetup t = tri_setup(vz, vy, vx, sd, d, h, w);
    double oz, oy, ox;
    gather_acc(src, t, vz, vy, vx, sd, oz, oy, ox);

    dst[p]           = (float)oz;
    dst[p + DHW]     = (float)oy;
    dst[p + 2 * DHW] = (float)ox;
}

// ---------- fallback SoA step (used only if ws too small) ----------

__global__ __launch_bounds__(256)
void vecint_step(const float* __restrict__ src, float* __restrict__ dst, float s) {
    int w, h, d;
    decode_tile(blockIdx.x, w, h, d);
    int p = d * HW + h * W + w;

    double vz = (double)src[p];
    double vy = (double)src[p + DHW];
    double vx = (double)src[p + 2 * DHW];
    double sd = (double)s;

    TriSetup t = tri_setup(vz, vy, vx, sd, d, h, w);

    int r00 = t.zc0 * HW + t.yc0 * W;
    int r01 = t.zc0 * HW + t.yc1 * W;
    int r10 = t.zc1 * HW + t.yc0 * W;
    int r11 = t.zc1 * HW + t.yc1 * W;
    int xc0 = t.s0hi ? t.bx + 1 : t.bx;
    int xc1 = t.s1lo ? t.bx : t.bx + 1;

    double ctr[3] = {vz, vy, vx};
    #pragma unroll
    for (int c = 0; c < 3; ++c) {
        const float* sc = src + c * DHW;
        double acc = ctr[c];
        acc += t.w000 * (double)sc[r00 + xc0];
        acc += t.w001 * (double)sc[r00 + xc1];
        acc += t.w010 * (double)sc[r01 + xc0];
        acc += t.w011 * (double)sc[r01 + xc1];
        acc += t.w100 * (double)sc[r10 + xc0];
        acc += t.w101 * (double)sc[r10 + xc1];
        acc += t.w110 * (double)sc[r11 + xc0];
        acc += t.w111 * (double)sc[r11 + xc1];
        dst[c * DHW + p] = (float)(sd * acc);
    }
}

extern "C" void kernel_launch(void* const* d_in, const int* in_sizes, int n_in,
                              void* d_out, int out_size, void* d_ws, size_t ws_size,
                              hipStream_t stream) {
    const float* vin = (const float*)d_in[0];
    float* out = (float*)d_out;

    dim3 tile_block(BX, BY, 1);
    dim3 tile_grid(NBLK, 1, 1);
    dim3 lin_block(256);
    dim3 lin_grid(DHW / 256);

    const size_t aos4_bytes = (size_t)DHW * sizeof(float4);

    if (ws_size >= 2 * aos4_bytes) {
        float4* A = (float4*)d_ws;
        float4* B = A + DHW;

        soa_to_aos4<<<lin_grid, lin_block, 0, stream>>>(vin, A);
        vecint_step4<true ><<<tile_grid, tile_block, 0, stream>>>(A, B);  // step 1
        vecint_step4<false><<<tile_grid, tile_block, 0, stream>>>(B, A);  // step 2
        vecint_step4<false><<<tile_grid, tile_block, 0, stream>>>(A, B);  // step 3
        vecint_step4<false><<<tile_grid, tile_block, 0, stream>>>(B, A);  // step 4
        vecint_step4<false><<<tile_grid, tile_block, 0, stream>>>(A, B);  // step 5
        vecint_step4<false><<<tile_grid, tile_block, 0, stream>>>(B, A);  // step 6
        vecint_step7<<<tile_grid, tile_block, 0, stream>>>(A, out);       // step 7 + unpack
    } else {
        // Fallback: SoA ping-pong d_out <-> d_ws.
        float* ws = (float*)d_ws;
        vecint_step<<<tile_grid, tile_block, 0, stream>>>(vin, out, 1.0f / 128.0f);
        const float* srcs[6] = {out, ws, out, ws, out, ws};
        float*       dsts[6] = {ws, out, ws, out, ws, out};
        for (int i = 0; i < 6; ++i)
            vecint_step<<<tile_grid, tile_block, 0, stream>>>(srcs[i], dsts[i], 1.0f);
    }
}